// Round 7
// baseline (126.294 us; speedup 1.0000x reference)
//
#include <hip/hip_runtime.h>
#include <hip/hip_fp16.h>

#define GNN_IN 128
#define HID 256
#define NSPLIT 4
#define SLICE 64  // HID / NSPLIT

typedef _Float16 f16x2 __attribute__((ext_vector_type(2)));
struct __align__(8) h4v { f16x2 a, b; };  // 4 fp16

__device__ __forceinline__ float fdot2f(f16x2 a, f16x2 b, float c) {
#if __has_builtin(__builtin_amdgcn_fdot2)
    return __builtin_amdgcn_fdot2(a, b, c, false);
#else
    return fmaf((float)a.x, (float)b.x, fmaf((float)a.y, (float)b.y, c));
#endif
}

__device__ __forceinline__ f16x2 pkcvt(float x, float y) {
#if __has_builtin(__builtin_amdgcn_cvt_pkrtz)
    return __builtin_bit_cast(f16x2, __builtin_amdgcn_cvt_pkrtz(x, y));
#else
    f16x2 r; r.x = (_Float16)x; r.y = (_Float16)y; return r;
#endif
}

#define DPP_ADD(v, ctrl)                                                     \
    do {                                                                     \
        float _t = __builtin_bit_cast(                                       \
            float, __builtin_amdgcn_update_dpp(                              \
                       0, __builtin_bit_cast(int, v), ctrl, 0xf, 0xf, true));\
        (v) += _t;                                                           \
    } while (0)

// sum over each 16-lane row; result in lane (row*16+15)
__device__ __forceinline__ float dpp_sum16(float v) {
    DPP_ADD(v, 0x111);  // row_shr:1
    DPP_ADD(v, 0x112);  // row_shr:2
    DPP_ADD(v, 0x114);  // row_shr:4
    DPP_ADD(v, 0x118);  // row_shr:8
    return v;
}

__device__ __forceinline__ float dpp_sum64(float v) {
    v = dpp_sum16(v);
    DPP_ADD(v, 0x142);  // row_bcast:15
    DPP_ADD(v, 0x143);  // row_bcast:31
    return v;           // lane 63 holds the wave total
}

// ---------------------------------------------------------------------------
// Detect int64 vs int32 edge_index (int64 little-endian high words are 0).
// ---------------------------------------------------------------------------
__global__ void detect_kernel(const unsigned int* __restrict__ ei,
                              unsigned int* __restrict__ flag) {
    if (threadIdx.x == 0 && blockIdx.x == 0) {
        unsigned int v = 0;
        for (int i = 1; i < 256; i += 2) v |= ei[i];
        *flag = (v == 0u) ? 1u : 0u;
    }
}

// ---------------------------------------------------------------------------
// Decode edge_index to packed int2 (row,col) regardless of input width.
// ---------------------------------------------------------------------------
__global__ void __launch_bounds__(256) decode_kernel(
    const void* __restrict__ ei, const unsigned int* __restrict__ flag,
    int2* __restrict__ idx, int ne) {
    const int e = blockIdx.x * 256 + threadIdx.x;
    if (e >= ne) return;
    if (*flag) {
        const int4 v = *(const int4*)((const char*)ei + (size_t)e * 16);
        idx[e] = make_int2(v.x, v.z);
    } else {
        idx[e] = ((const int2*)ei)[e];
    }
}

// ---------------------------------------------------------------------------
// Phase 1: [A|B] = x @ [w1_top|w1_bot] -> fp16.  16 rows/block, 256 threads
// = 128 col-quads x 2 row-groups (C=4: one ds_read_b128 feeds 16 fma).
// ---------------------------------------------------------------------------
__global__ void __launch_bounds__(256) node_gemm_c4(
    const float* __restrict__ x, const float* __restrict__ w1,
    __half* __restrict__ AB, int num_nodes) {
    __shared__ float xs[16][GNN_IN];
    const int tid = threadIdx.x;
    const int r0  = blockIdx.x * 16;

    for (int i = tid; i < 16 * GNN_IN / 4; i += 256) {
        const int rr = i >> 5;
        const int cc = (i & 31) << 2;
        const int r = min(r0 + rr, num_nodes - 1);
        *(float4*)&xs[rr][cc] = *(const float4*)(x + (size_t)r * GNN_IN + cc);
    }
    __syncthreads();

    const int cq   = tid & 127;        // col-quad over 512 concat cols
    const int rg   = tid >> 7;         // row group: rows rg*8 .. rg*8+7
    const int col  = (cq & 63) << 2;   // column within half
    const int half = cq >> 6;          // 0 = A-half, 1 = B-half
    const float* __restrict__ w = w1 + (size_t)half * GNN_IN * HID + col;

    float acc[8][4];
#pragma unroll
    for (int r = 0; r < 8; ++r)
#pragma unroll
        for (int c = 0; c < 4; ++c) acc[r][c] = 0.f;

    for (int k0 = 0; k0 < GNN_IN; k0 += 4) {
        float4 wv[4];
#pragma unroll
        for (int kk = 0; kk < 4; ++kk)
            wv[kk] = *(const float4*)(w + (size_t)(k0 + kk) * HID);
#pragma unroll
        for (int r = 0; r < 8; ++r) {
            const float4 xv = *(const float4*)&xs[rg * 8 + r][k0];
            acc[r][0] = fmaf(xv.x, wv[0].x, acc[r][0]);
            acc[r][1] = fmaf(xv.x, wv[0].y, acc[r][1]);
            acc[r][2] = fmaf(xv.x, wv[0].z, acc[r][2]);
            acc[r][3] = fmaf(xv.x, wv[0].w, acc[r][3]);
            acc[r][0] = fmaf(xv.y, wv[1].x, acc[r][0]);
            acc[r][1] = fmaf(xv.y, wv[1].y, acc[r][1]);
            acc[r][2] = fmaf(xv.y, wv[1].z, acc[r][2]);
            acc[r][3] = fmaf(xv.y, wv[1].w, acc[r][3]);
            acc[r][0] = fmaf(xv.z, wv[2].x, acc[r][0]);
            acc[r][1] = fmaf(xv.z, wv[2].y, acc[r][1]);
            acc[r][2] = fmaf(xv.z, wv[2].z, acc[r][2]);
            acc[r][3] = fmaf(xv.z, wv[2].w, acc[r][3]);
            acc[r][0] = fmaf(xv.w, wv[3].x, acc[r][0]);
            acc[r][1] = fmaf(xv.w, wv[3].y, acc[r][1]);
            acc[r][2] = fmaf(xv.w, wv[3].z, acc[r][2]);
            acc[r][3] = fmaf(xv.w, wv[3].w, acc[r][3]);
        }
    }

    __half* o = AB + (size_t)half * num_nodes * HID + col;
#pragma unroll
    for (int r = 0; r < 8; ++r) {
        const int rr = r0 + rg * 8 + r;
        if (rr < num_nodes) {
            h4v hv;
            hv.a = pkcvt(acc[r][0], acc[r][1]);
            hv.b = pkcvt(acc[r][2], acc[r][3]);
            *(h4v*)(o + (size_t)rr * HID) = hv;
        }
    }
}

// ---------------------------------------------------------------------------
// Phase 2a: column-split edge pass. Each block owns column slice
// split = (blockIdx%8)>>1 so the slice's A/B columns stay L2-resident on its
// XCD pair. 16 lanes x 4 cols per edge, 4 edges per wave-iteration.
// partials[split*ne + e] = dot(h_slice, w2_slice).
// ---------------------------------------------------------------------------
__global__ void __launch_bounds__(256) edge_split_kernel(
    const __half* __restrict__ AB, const int2* __restrict__ idx,
    const float* __restrict__ ed, const float* __restrict__ w1,
    const float* __restrict__ b1, const float* __restrict__ w2,
    float* __restrict__ partials, int num_edges, int num_nodes) {
    const int tid   = threadIdx.x;
    const int lane  = tid & 63;
    const int bid   = blockIdx.x;
    const int split = (bid & 7) >> 1;
    const int wsi   = ((((bid >> 3) << 1) | (bid & 1)) << 2) | (tid >> 6);
    const int nsw   = (gridDim.x >> 3) << 3;  // (grid/8)*2*4 waves per split
    const int j     = lane >> 4;              // edge-in-group
    const int q     = lane & 15;              // col-quad in slice
    const int c     = split * SLICE + (q << 2);

    const float4 b1v = *(const float4*)(b1 + c);
    const float  b1a[4] = {b1v.x, b1v.y, b1v.z, b1v.w};
    f16x2 wt01[4], wt23[4];
#pragma unroll
    for (int cc = 0; cc < 4; ++cc) {
        wt01[cc] = pkcvt(w1[(size_t)(2 * GNN_IN + 0) * HID + c + cc],
                         w1[(size_t)(2 * GNN_IN + 1) * HID + c + cc]);
        wt23[cc] = pkcvt(w1[(size_t)(2 * GNN_IN + 2) * HID + c + cc],
                         w1[(size_t)(2 * GNN_IN + 3) * HID + c + cc]);
    }
    const float4 w2f = *(const float4*)(w2 + c);
    const f16x2  w2A = pkcvt(w2f.x, w2f.y);
    const f16x2  w2B = pkcvt(w2f.z, w2f.w);
    const f16x2 zero = {(_Float16)0.f, (_Float16)0.f};

    const __half* __restrict__ A = AB;
    const __half* __restrict__ B = AB + (size_t)num_nodes * HID;
    const int ngroups = (num_edges + 3) >> 2;

    for (int grp = wsi; grp < ngroups; grp += nsw) {
        const int e = min(grp * 4 + j, num_edges - 1);
        const int2 rc = idx[e];
        const float4 edv = *(const float4*)(ed + (size_t)e * 4);
        const h4v av = *(const h4v*)(A + (size_t)rc.x * HID + c);
        const h4v bv = *(const h4v*)(B + (size_t)rc.y * HID + c);

        const f16x2 e01 = pkcvt(edv.x, edv.y);
        const f16x2 e23 = pkcvt(edv.z, edv.w);
        float c_[4];
#pragma unroll
        for (int cc = 0; cc < 4; ++cc)
            c_[cc] = fdot2f(e01, wt01[cc], fdot2f(e23, wt23[cc], b1a[cc]));

        f16x2 h0 = (av.a + bv.a) + pkcvt(c_[0], c_[1]);
        f16x2 h1 = (av.b + bv.b) + pkcvt(c_[2], c_[3]);
        h0 = __builtin_elementwise_max(h0, zero);
        h1 = __builtin_elementwise_max(h1, zero);
        float p = fdot2f(h0, w2A, fdot2f(h1, w2B, 0.f));

        p = dpp_sum16(p);
        if (q == 15) partials[(size_t)split * num_edges + e] = p;
    }
}

// ---------------------------------------------------------------------------
// Phase 2b: combine 4 partials + bias + sigmoid.
// ---------------------------------------------------------------------------
__global__ void __launch_bounds__(256) combine_kernel(
    const float* __restrict__ partials, const float* __restrict__ b2,
    float* __restrict__ out, int ne) {
    const int e = blockIdx.x * 256 + threadIdx.x;
    if (e >= ne) return;
    const float p = partials[e] + partials[(size_t)ne + e] +
                    partials[(size_t)2 * ne + e] + partials[(size_t)3 * ne + e];
    out[e] = 1.f / (1.f + __expf(-(p + b2[0])));
}

// ---------------------------------------------------------------------------
// Fallback A (ws >= 10.5 MB): round-6 single edge kernel.
// ---------------------------------------------------------------------------
__global__ void __launch_bounds__(256) edge_kernel_fp16(
    const __half* __restrict__ A, const __half* __restrict__ B,
    const void* __restrict__ ei, const float* __restrict__ ed,
    const float* __restrict__ w1, const float* __restrict__ b1,
    const float* __restrict__ w2, const float* __restrict__ b2,
    const unsigned int* __restrict__ flag,
    float* __restrict__ out, int num_edges) {
    const int lane   = threadIdx.x & 63;
    const int wave   = (blockIdx.x * blockDim.x + threadIdx.x) >> 6;
    const int nwaves = (gridDim.x * blockDim.x) >> 6;
    const int c0     = lane << 2;

    const float4 b1v = *(const float4*)(b1 + c0);
    float wt[4][4];
#pragma unroll
    for (int k = 0; k < 4; ++k)
        *(float4*)wt[k] = *(const float4*)(w1 + (size_t)(2 * GNN_IN + k) * HID + c0);
    const float4 w2f = *(const float4*)(w2 + c0);
    const f16x2  w2A = pkcvt(w2f.x, w2f.y);
    const f16x2  w2B = pkcvt(w2f.z, w2f.w);
    const float  b2v = b2[0];
    const int   is64 = __builtin_amdgcn_readfirstlane((int)(*flag));
    const f16x2 zero = {(_Float16)0.f, (_Float16)0.f};

    const int chunk = (((num_edges + nwaves - 1) / nwaves) + 3) & ~3;
    const int e0s = __builtin_amdgcn_readfirstlane(wave * chunk);
    const int e1s = __builtin_amdgcn_readfirstlane(min(num_edges, e0s + chunk));

    for (int es = e0s; es < e1s; es += 4) {
        int eid[4];
#pragma unroll
        for (int jj = 0; jj < 4; ++jj) eid[jj] = min(es + jj, e1s - 1);
        int rr[4], cc[4];
        if (is64) {
#pragma unroll
            for (int jj = 0; jj < 4; ++jj) {
                const int4 v = *(const int4*)((const char*)ei + (size_t)eid[jj] * 16);
                rr[jj] = v.x; cc[jj] = v.z;
            }
        } else {
#pragma unroll
            for (int jj = 0; jj < 4; ++jj) {
                const int2 v = *(const int2*)((const char*)ei + (size_t)eid[jj] * 8);
                rr[jj] = v.x; cc[jj] = v.y;
            }
        }
        h4v av[4], bv[4];
        float4 edv[4];
#pragma unroll
        for (int jj = 0; jj < 4; ++jj) {
            av[jj]  = *(const h4v*)(A + (size_t)rr[jj] * HID + c0);
            bv[jj]  = *(const h4v*)(B + (size_t)cc[jj] * HID + c0);
            edv[jj] = *(const float4*)(ed + (size_t)eid[jj] * 4);
        }
        float p[4];
#pragma unroll
        for (int jj = 0; jj < 4; ++jj) {
            float c_[4] = {b1v.x, b1v.y, b1v.z, b1v.w};
            const float ep[4] = {edv[jj].x, edv[jj].y, edv[jj].z, edv[jj].w};
#pragma unroll
            for (int k = 0; k < 4; ++k)
#pragma unroll
                for (int qq = 0; qq < 4; ++qq) c_[qq] = fmaf(ep[k], wt[k][qq], c_[qq]);
            f16x2 h0 = (av[jj].a + bv[jj].a) + pkcvt(c_[0], c_[1]);
            f16x2 h1 = (av[jj].b + bv[jj].b) + pkcvt(c_[2], c_[3]);
            h0 = __builtin_elementwise_max(h0, zero);
            h1 = __builtin_elementwise_max(h1, zero);
            p[jj] = fdot2f(h0, w2A, fdot2f(h1, w2B, 0.f));
        }
#pragma unroll
        for (int jj = 0; jj < 4; ++jj) p[jj] = dpp_sum64(p[jj]);
        float s[4];
#pragma unroll
        for (int jj = 0; jj < 4; ++jj) s[jj] = 1.f / (1.f + __expf(-(p[jj] + b2v)));
        if (lane == 63) {
            if (es + 3 < e1s) {
                *(float4*)(out + es) = make_float4(s[0], s[1], s[2], s[3]);
            } else {
#pragma unroll
                for (int jj = 0; jj < 4; ++jj)
                    if (es + jj < e1s) out[es + jj] = s[jj];
            }
        }
    }
}

// ---------------------------------------------------------------------------
// Fallback B (tiny ws): direct per-edge fp32.
// ---------------------------------------------------------------------------
__global__ void __launch_bounds__(256) edge_direct_kernel(
    const float* __restrict__ x, const void* __restrict__ ei,
    const float* __restrict__ ed, const float* __restrict__ w1,
    const float* __restrict__ b1, const float* __restrict__ w2,
    const float* __restrict__ b2, const unsigned int* __restrict__ flag,
    float* __restrict__ out, int num_edges, int num_nodes) {
    const int lane   = threadIdx.x & 63;
    const int wave   = (blockIdx.x * blockDim.x + threadIdx.x) >> 6;
    const int nwaves = (gridDim.x * blockDim.x) >> 6;
    const int c0     = lane << 2;

    const float4 w2v = *(const float4*)(w2 + c0);
    const float4 b1v = *(const float4*)(b1 + c0);
    float wt[4][4];
#pragma unroll
    for (int k = 0; k < 4; ++k)
        *(float4*)wt[k] = *(const float4*)(w1 + (size_t)(2 * GNN_IN + k) * HID + c0);
    const float b2v  = b2[0];
    const int   is64 = flag ? (int)(*flag) : 0;
    const float* w2p = (const float*)&w2v;
    const float* b1p = (const float*)&b1v;

    const int chunk = (num_edges + nwaves - 1) / nwaves;
    const int e0 = wave * chunk;
    const int e1 = min(num_edges, e0 + chunk);

    for (int e = e0; e < e1; ++e) {
        int row, col;
        if (is64) {
            const int4 v = ((const int4*)ei)[e];
            row = v.x; col = v.z;
        } else {
            const int2 v = ((const int2*)ei)[e];
            row = v.x; col = v.y;
        }
        row = min(max(row, 0), num_nodes - 1);
        col = min(max(col, 0), num_nodes - 1);
        const float4 edv = *(const float4*)(ed + (size_t)e * 4);
        const float* edp = (const float*)&edv;
        float h4[4];
#pragma unroll
        for (int jj = 0; jj < 4; ++jj) {
            float h = b1p[jj];
#pragma unroll
            for (int k = 0; k < 4; ++k) h = fmaf(edp[k], wt[k][jj], h);
            h4[jj] = h;
        }
        const float* xr = x + (size_t)row * GNN_IN;
        const float* xc = x + (size_t)col * GNN_IN;
        for (int k = 0; k < GNN_IN; ++k) {
            const float xv = xr[k];
            const float4 wv = *(const float4*)(w1 + (size_t)k * HID + c0);
            h4[0] = fmaf(xv, wv.x, h4[0]); h4[1] = fmaf(xv, wv.y, h4[1]);
            h4[2] = fmaf(xv, wv.z, h4[2]); h4[3] = fmaf(xv, wv.w, h4[3]);
        }
        for (int k = 0; k < GNN_IN; ++k) {
            const float xv = xc[k];
            const float4 wv = *(const float4*)(w1 + (size_t)(GNN_IN + k) * HID + c0);
            h4[0] = fmaf(xv, wv.x, h4[0]); h4[1] = fmaf(xv, wv.y, h4[1]);
            h4[2] = fmaf(xv, wv.z, h4[2]); h4[3] = fmaf(xv, wv.w, h4[3]);
        }
        float p = 0.f;
#pragma unroll
        for (int jj = 0; jj < 4; ++jj) p = fmaf(fmaxf(h4[jj], 0.f), w2p[jj], p);
#pragma unroll
        for (int off = 32; off >= 1; off >>= 1) p += __shfl_xor(p, off, 64);
        if (lane == 0) out[e] = 1.f / (1.f + __expf(-(p + b2v)));
    }
}

extern "C" void kernel_launch(void* const* d_in, const int* in_sizes, int n_in,
                              void* d_out, int out_size, void* d_ws, size_t ws_size,
                              hipStream_t stream) {
    const float* x  = (const float*)d_in[0];
    const void*  ei = d_in[1];
    const float* ed = (const float*)d_in[2];
    const float* w1 = (const float*)d_in[3];
    const float* b1 = (const float*)d_in[4];
    const float* w2 = (const float*)d_in[5];
    const float* b2 = (const float*)d_in[6];
    float* out = (float*)d_out;

    const int num_nodes = in_sizes[0] / GNN_IN;  // 10000
    const int num_edges = in_sizes[1] / 2;       // 640000

    unsigned int* flag = nullptr;
    if (ws_size >= 16) {
        flag = (unsigned int*)d_ws;
        detect_kernel<<<1, 64, 0, stream>>>((const unsigned int*)ei, flag);
    }

    const size_t ab_bytes   = (size_t)2 * num_nodes * HID * sizeof(__half);
    const size_t idx_bytes  = (size_t)num_edges * sizeof(int2);
    const size_t part_bytes = (size_t)NSPLIT * num_edges * sizeof(float);
    const size_t need_split = 256 + ab_bytes + idx_bytes + part_bytes;
    const size_t need_old   = 256 + ab_bytes;

    if (flag && ws_size >= need_split) {
        __half* AB      = (__half*)((char*)d_ws + 256);
        int2*   idx     = (int2*)((char*)d_ws + 256 + ab_bytes);
        float*  partial = (float*)((char*)d_ws + 256 + ab_bytes + idx_bytes);

        decode_kernel<<<(num_edges + 255) / 256, 256, 0, stream>>>(ei, flag, idx,
                                                                   num_edges);
        node_gemm_c4<<<(num_nodes + 15) / 16, 256, 0, stream>>>(x, w1, AB,
                                                                num_nodes);
        edge_split_kernel<<<2048, 256, 0, stream>>>(AB, idx, ed, w1, b1, w2,
                                                    partial, num_edges, num_nodes);
        combine_kernel<<<(num_edges + 255) / 256, 256, 0, stream>>>(partial, b2,
                                                                    out, num_edges);
    } else if (flag && ws_size >= need_old) {
        __half* AB = (__half*)((char*)d_ws + 256);
        node_gemm_c4<<<(num_nodes + 15) / 16, 256, 0, stream>>>(x, w1, AB,
                                                                num_nodes);
        __half* Bp = AB + (size_t)num_nodes * HID;
        edge_kernel_fp16<<<2048, 256, 0, stream>>>(AB, Bp, ei, ed, w1, b1, w2, b2,
                                                   flag, out, num_edges);
    } else {
        edge_direct_kernel<<<4096, 256, 0, stream>>>(x, ei, ed, w1, b1, w2, b2,
                                                     flag, out, num_edges, num_nodes);
    }
}

// Round 8
// 100.590 us; speedup vs baseline: 1.2555x; 1.2555x over previous
//
#include <hip/hip_runtime.h>
#include <hip/hip_fp16.h>

#define GNN_IN 128
#define HID 256
#define NSPLIT 4
#define SLICE 64  // HID / NSPLIT

typedef _Float16 f16x2 __attribute__((ext_vector_type(2)));
struct __align__(8) h4v { f16x2 a, b; };            // 4 fp16
struct __align__(16) h8v { f16x2 a, b, c, d; };     // 8 fp16

__device__ __forceinline__ float fdot2f(f16x2 a, f16x2 b, float c) {
#if __has_builtin(__builtin_amdgcn_fdot2)
    return __builtin_amdgcn_fdot2(a, b, c, false);
#else
    return fmaf((float)a.x, (float)b.x, fmaf((float)a.y, (float)b.y, c));
#endif
}

__device__ __forceinline__ f16x2 pkcvt(float x, float y) {
#if __has_builtin(__builtin_amdgcn_cvt_pkrtz)
    return __builtin_bit_cast(f16x2, __builtin_amdgcn_cvt_pkrtz(x, y));
#else
    f16x2 r; r.x = (_Float16)x; r.y = (_Float16)y; return r;
#endif
}

#define DPP_ADD(v, ctrl)                                                     \
    do {                                                                     \
        float _t = __builtin_bit_cast(                                       \
            float, __builtin_amdgcn_update_dpp(                              \
                       0, __builtin_bit_cast(int, v), ctrl, 0xf, 0xf, true));\
        (v) += _t;                                                           \
    } while (0)

// sum over 8-lane groups; lanes with (lane&7)==7 hold their group's total
__device__ __forceinline__ float dpp_sum8(float v) {
    DPP_ADD(v, 0x111);  // row_shr:1
    DPP_ADD(v, 0x112);  // row_shr:2
    DPP_ADD(v, 0x114);  // row_shr:4
    return v;
}

__device__ __forceinline__ float dpp_sum64(float v) {
    DPP_ADD(v, 0x111);
    DPP_ADD(v, 0x112);
    DPP_ADD(v, 0x114);
    DPP_ADD(v, 0x118);
    DPP_ADD(v, 0x142);  // row_bcast:15
    DPP_ADD(v, 0x143);  // row_bcast:31
    return v;           // lane 63 holds the wave total
}

// ---------------------------------------------------------------------------
// Detect int64 vs int32 edge_index (int64 little-endian high words are 0).
// ---------------------------------------------------------------------------
__global__ void detect_kernel(const unsigned int* __restrict__ ei,
                              unsigned int* __restrict__ flag) {
    if (threadIdx.x == 0 && blockIdx.x == 0) {
        unsigned int v = 0;
        for (int i = 1; i < 256; i += 2) v |= ei[i];
        *flag = (v == 0u) ? 1u : 0u;
    }
}

// ---------------------------------------------------------------------------
// Decode edge_index to packed int2 (row,col) regardless of input width.
// ---------------------------------------------------------------------------
__global__ void __launch_bounds__(256) decode_kernel(
    const void* __restrict__ ei, const unsigned int* __restrict__ flag,
    int2* __restrict__ idx, int ne) {
    const int e = blockIdx.x * 256 + threadIdx.x;
    if (e >= ne) return;
    if (*flag) {
        const int4 v = *(const int4*)((const char*)ei + (size_t)e * 16);
        idx[e] = make_int2(v.x, v.z);
    } else {
        idx[e] = ((const int2*)ei)[e];
    }
}

// ---------------------------------------------------------------------------
// Phase 1: [A|B] = x @ [w1_top|w1_bot] -> fp16.  16 rows/block, 256 threads
// = 128 col-quads x 2 row-groups (C=4: one ds_read_b128 feeds 16 fma).
// ---------------------------------------------------------------------------
__global__ void __launch_bounds__(256) node_gemm_c4(
    const float* __restrict__ x, const float* __restrict__ w1,
    __half* __restrict__ AB, int num_nodes) {
    __shared__ float xs[16][GNN_IN];
    const int tid = threadIdx.x;
    const int r0  = blockIdx.x * 16;

    for (int i = tid; i < 16 * GNN_IN / 4; i += 256) {
        const int rr = i >> 5;
        const int cc = (i & 31) << 2;
        const int r = min(r0 + rr, num_nodes - 1);
        *(float4*)&xs[rr][cc] = *(const float4*)(x + (size_t)r * GNN_IN + cc);
    }
    __syncthreads();

    const int cq   = tid & 127;
    const int rg   = tid >> 7;
    const int col  = (cq & 63) << 2;
    const int half = cq >> 6;
    const float* __restrict__ w = w1 + (size_t)half * GNN_IN * HID + col;

    float acc[8][4];
#pragma unroll
    for (int r = 0; r < 8; ++r)
#pragma unroll
        for (int c = 0; c < 4; ++c) acc[r][c] = 0.f;

    for (int k0 = 0; k0 < GNN_IN; k0 += 4) {
        float4 wv[4];
#pragma unroll
        for (int kk = 0; kk < 4; ++kk)
            wv[kk] = *(const float4*)(w + (size_t)(k0 + kk) * HID);
#pragma unroll
        for (int r = 0; r < 8; ++r) {
            const float4 xv = *(const float4*)&xs[rg * 8 + r][k0];
            acc[r][0] = fmaf(xv.x, wv[0].x, acc[r][0]);
            acc[r][1] = fmaf(xv.x, wv[0].y, acc[r][1]);
            acc[r][2] = fmaf(xv.x, wv[0].z, acc[r][2]);
            acc[r][3] = fmaf(xv.x, wv[0].w, acc[r][3]);
            acc[r][0] = fmaf(xv.y, wv[1].x, acc[r][0]);
            acc[r][1] = fmaf(xv.y, wv[1].y, acc[r][1]);
            acc[r][2] = fmaf(xv.y, wv[1].z, acc[r][2]);
            acc[r][3] = fmaf(xv.y, wv[1].w, acc[r][3]);
            acc[r][0] = fmaf(xv.z, wv[2].x, acc[r][0]);
            acc[r][1] = fmaf(xv.z, wv[2].y, acc[r][1]);
            acc[r][2] = fmaf(xv.z, wv[2].z, acc[r][2]);
            acc[r][3] = fmaf(xv.z, wv[2].w, acc[r][3]);
            acc[r][0] = fmaf(xv.w, wv[3].x, acc[r][0]);
            acc[r][1] = fmaf(xv.w, wv[3].y, acc[r][1]);
            acc[r][2] = fmaf(xv.w, wv[3].z, acc[r][2]);
            acc[r][3] = fmaf(xv.w, wv[3].w, acc[r][3]);
        }
    }

    __half* o = AB + (size_t)half * num_nodes * HID + col;
#pragma unroll
    for (int r = 0; r < 8; ++r) {
        const int rr = r0 + rg * 8 + r;
        if (rr < num_nodes) {
            h4v hv;
            hv.a = pkcvt(acc[r][0], acc[r][1]);
            hv.b = pkcvt(acc[r][2], acc[r][3]);
            *(h4v*)(o + (size_t)rr * HID) = hv;
        }
    }
}

// ---------------------------------------------------------------------------
// Phase 2a: column-split edge pass, v2.
// split = (blockIdx%8)>>1 keeps each 64-col slice L2-resident on an XCD pair.
// Layout: 8 lanes per edge (16B gathers, 8 cols/lane), 8 edges per wave-iter,
// two interleaved groups per loop iteration for MLP.
// ---------------------------------------------------------------------------
__global__ void __launch_bounds__(256) edge_split_kernel(
    const __half* __restrict__ AB, const int2* __restrict__ idx,
    const float* __restrict__ ed, const float* __restrict__ w1,
    const float* __restrict__ b1, const float* __restrict__ w2,
    float* __restrict__ partials, int num_edges, int num_nodes) {
    const int tid   = threadIdx.x;
    const int lane  = tid & 63;
    const int bid   = blockIdx.x;
    const int split = (bid & 7) >> 1;
    const int wsi   = ((((bid >> 3) << 1) | (bid & 1)) << 2) | (tid >> 6);
    const int nsw   = (gridDim.x >> 3) << 3;   // waves per split
    const int j8    = lane >> 3;               // edge-in-group 0..7
    const int q8    = lane & 7;                // col-oct in slice
    const int c     = split * SLICE + (q8 << 3);

    // per-lane constants for my 8 columns
    f16x2 wtA[8], wtB[8], w2pk[4];
    float b1f[8];
#pragma unroll
    for (int cc = 0; cc < 8; ++cc) {
        wtA[cc] = pkcvt(w1[(size_t)(2 * GNN_IN + 0) * HID + c + cc],
                        w1[(size_t)(2 * GNN_IN + 1) * HID + c + cc]);
        wtB[cc] = pkcvt(w1[(size_t)(2 * GNN_IN + 2) * HID + c + cc],
                        w1[(size_t)(2 * GNN_IN + 3) * HID + c + cc]);
        b1f[cc] = b1[c + cc];
    }
#pragma unroll
    for (int m = 0; m < 4; ++m)
        w2pk[m] = pkcvt(w2[c + 2 * m], w2[c + 2 * m + 1]);
    const f16x2 zero = {(_Float16)0.f, (_Float16)0.f};

    const __half* __restrict__ A = AB;
    const __half* __restrict__ B = AB + (size_t)num_nodes * HID;
    float* __restrict__ pbase = partials + (size_t)split * num_edges;
    const int ngroups = (num_edges + 7) >> 3;

    for (int g0 = wsi; g0 < ngroups; g0 += 2 * nsw) {
        const int g1 = min(g0 + nsw, ngroups - 1);
        const int e0 = min(g0 * 8 + j8, num_edges - 1);
        const int e1 = min(g1 * 8 + j8, num_edges - 1);

        // issue all loads for both groups
        const int2  rc0 = idx[e0];
        const int2  rc1 = idx[e1];
        const float4 edv0 = *(const float4*)(ed + (size_t)e0 * 4);
        const float4 edv1 = *(const float4*)(ed + (size_t)e1 * 4);
        const h8v av0 = *(const h8v*)(A + (size_t)rc0.x * HID + c);
        const h8v bv0 = *(const h8v*)(B + (size_t)rc0.y * HID + c);
        const h8v av1 = *(const h8v*)(A + (size_t)rc1.x * HID + c);
        const h8v bv1 = *(const h8v*)(B + (size_t)rc1.y * HID + c);

        float p0, p1;
        {
            const f16x2 e01 = pkcvt(edv0.x, edv0.y);
            const f16x2 e23 = pkcvt(edv0.z, edv0.w);
            float c_[8];
#pragma unroll
            for (int cc = 0; cc < 8; ++cc)
                c_[cc] = fdot2f(e23, wtB[cc], fdot2f(e01, wtA[cc], b1f[cc]));
            f16x2 h0 = (av0.a + bv0.a) + pkcvt(c_[0], c_[1]);
            f16x2 h1 = (av0.b + bv0.b) + pkcvt(c_[2], c_[3]);
            f16x2 h2 = (av0.c + bv0.c) + pkcvt(c_[4], c_[5]);
            f16x2 h3 = (av0.d + bv0.d) + pkcvt(c_[6], c_[7]);
            h0 = __builtin_elementwise_max(h0, zero);
            h1 = __builtin_elementwise_max(h1, zero);
            h2 = __builtin_elementwise_max(h2, zero);
            h3 = __builtin_elementwise_max(h3, zero);
            p0 = fdot2f(h0, w2pk[0],
                 fdot2f(h1, w2pk[1], fdot2f(h2, w2pk[2], fdot2f(h3, w2pk[3], 0.f))));
        }
        {
            const f16x2 e01 = pkcvt(edv1.x, edv1.y);
            const f16x2 e23 = pkcvt(edv1.z, edv1.w);
            float c_[8];
#pragma unroll
            for (int cc = 0; cc < 8; ++cc)
                c_[cc] = fdot2f(e23, wtB[cc], fdot2f(e01, wtA[cc], b1f[cc]));
            f16x2 h0 = (av1.a + bv1.a) + pkcvt(c_[0], c_[1]);
            f16x2 h1 = (av1.b + bv1.b) + pkcvt(c_[2], c_[3]);
            f16x2 h2 = (av1.c + bv1.c) + pkcvt(c_[4], c_[5]);
            f16x2 h3 = (av1.d + bv1.d) + pkcvt(c_[6], c_[7]);
            h0 = __builtin_elementwise_max(h0, zero);
            h1 = __builtin_elementwise_max(h1, zero);
            h2 = __builtin_elementwise_max(h2, zero);
            h3 = __builtin_elementwise_max(h3, zero);
            p1 = fdot2f(h0, w2pk[0],
                 fdot2f(h1, w2pk[1], fdot2f(h2, w2pk[2], fdot2f(h3, w2pk[3], 0.f))));
        }

        p0 = dpp_sum8(p0);
        p1 = dpp_sum8(p1);
        if (q8 == 7) {
            pbase[e0] = p0;
            if (g1 != g0) pbase[e1] = p1;
        }
    }
}

// ---------------------------------------------------------------------------
// Phase 2b: combine 4 partials + bias + sigmoid, 4 edges per thread.
// ---------------------------------------------------------------------------
__global__ void __launch_bounds__(256) combine_kernel(
    const float* __restrict__ partials, const float* __restrict__ b2,
    float* __restrict__ out, int ne) {
    const int e0 = (blockIdx.x * 256 + threadIdx.x) * 4;
    if (e0 >= ne) return;
    const float b2v = b2[0];
    if (e0 + 3 < ne) {
        float4 s0 = *(const float4*)(partials + e0);
        const float4 s1 = *(const float4*)(partials + (size_t)ne + e0);
        const float4 s2 = *(const float4*)(partials + (size_t)2 * ne + e0);
        const float4 s3 = *(const float4*)(partials + (size_t)3 * ne + e0);
        s0.x = 1.f / (1.f + __expf(-(s0.x + s1.x + s2.x + s3.x + b2v)));
        s0.y = 1.f / (1.f + __expf(-(s0.y + s1.y + s2.y + s3.y + b2v)));
        s0.z = 1.f / (1.f + __expf(-(s0.z + s1.z + s2.z + s3.z + b2v)));
        s0.w = 1.f / (1.f + __expf(-(s0.w + s1.w + s2.w + s3.w + b2v)));
        *(float4*)(out + e0) = s0;
    } else {
        for (int e = e0; e < ne; ++e) {
            const float p = partials[e] + partials[(size_t)ne + e] +
                            partials[(size_t)2 * ne + e] +
                            partials[(size_t)3 * ne + e];
            out[e] = 1.f / (1.f + __expf(-(p + b2v)));
        }
    }
}

// ---------------------------------------------------------------------------
// Fallback A (ws >= AB only): round-6 full-row edge kernel.
// ---------------------------------------------------------------------------
__global__ void __launch_bounds__(256) edge_kernel_fp16(
    const __half* __restrict__ A, const __half* __restrict__ B,
    const void* __restrict__ ei, const float* __restrict__ ed,
    const float* __restrict__ w1, const float* __restrict__ b1,
    const float* __restrict__ w2, const float* __restrict__ b2,
    const unsigned int* __restrict__ flag,
    float* __restrict__ out, int num_edges) {
    const int lane   = threadIdx.x & 63;
    const int wave   = (blockIdx.x * blockDim.x + threadIdx.x) >> 6;
    const int nwaves = (gridDim.x * blockDim.x) >> 6;
    const int c0     = lane << 2;

    const float4 b1v = *(const float4*)(b1 + c0);
    float wt[4][4];
#pragma unroll
    for (int k = 0; k < 4; ++k)
        *(float4*)wt[k] = *(const float4*)(w1 + (size_t)(2 * GNN_IN + k) * HID + c0);
    const float4 w2f = *(const float4*)(w2 + c0);
    const f16x2  w2A = pkcvt(w2f.x, w2f.y);
    const f16x2  w2B = pkcvt(w2f.z, w2f.w);
    const float  b2v = b2[0];
    const int   is64 = __builtin_amdgcn_readfirstlane((int)(*flag));
    const f16x2 zero = {(_Float16)0.f, (_Float16)0.f};

    const int chunk = (((num_edges + nwaves - 1) / nwaves) + 3) & ~3;
    const int e0s = __builtin_amdgcn_readfirstlane(wave * chunk);
    const int e1s = __builtin_amdgcn_readfirstlane(min(num_edges, e0s + chunk));

    for (int es = e0s; es < e1s; es += 4) {
        int eid[4];
#pragma unroll
        for (int jj = 0; jj < 4; ++jj) eid[jj] = min(es + jj, e1s - 1);
        int rr[4], cc[4];
        if (is64) {
#pragma unroll
            for (int jj = 0; jj < 4; ++jj) {
                const int4 v = *(const int4*)((const char*)ei + (size_t)eid[jj] * 16);
                rr[jj] = v.x; cc[jj] = v.z;
            }
        } else {
#pragma unroll
            for (int jj = 0; jj < 4; ++jj) {
                const int2 v = *(const int2*)((const char*)ei + (size_t)eid[jj] * 8);
                rr[jj] = v.x; cc[jj] = v.y;
            }
        }
        h4v av[4], bv[4];
        float4 edv[4];
#pragma unroll
        for (int jj = 0; jj < 4; ++jj) {
            av[jj]  = *(const h4v*)(A + (size_t)rr[jj] * HID + c0);
            bv[jj]  = *(const h4v*)(B + (size_t)cc[jj] * HID + c0);
            edv[jj] = *(const float4*)(ed + (size_t)eid[jj] * 4);
        }
        float p[4];
#pragma unroll
        for (int jj = 0; jj < 4; ++jj) {
            float c_[4] = {b1v.x, b1v.y, b1v.z, b1v.w};
            const float ep[4] = {edv[jj].x, edv[jj].y, edv[jj].z, edv[jj].w};
#pragma unroll
            for (int k = 0; k < 4; ++k)
#pragma unroll
                for (int qq = 0; qq < 4; ++qq) c_[qq] = fmaf(ep[k], wt[k][qq], c_[qq]);
            f16x2 h0 = (av[jj].a + bv[jj].a) + pkcvt(c_[0], c_[1]);
            f16x2 h1 = (av[jj].b + bv[jj].b) + pkcvt(c_[2], c_[3]);
            h0 = __builtin_elementwise_max(h0, zero);
            h1 = __builtin_elementwise_max(h1, zero);
            p[jj] = fdot2f(h0, w2A, fdot2f(h1, w2B, 0.f));
        }
#pragma unroll
        for (int jj = 0; jj < 4; ++jj) p[jj] = dpp_sum64(p[jj]);
        float s[4];
#pragma unroll
        for (int jj = 0; jj < 4; ++jj) s[jj] = 1.f / (1.f + __expf(-(p[jj] + b2v)));
        if (lane == 63) {
            if (es + 3 < e1s) {
                *(float4*)(out + es) = make_float4(s[0], s[1], s[2], s[3]);
            } else {
#pragma unroll
                for (int jj = 0; jj < 4; ++jj)
                    if (es + jj < e1s) out[es + jj] = s[jj];
            }
        }
    }
}

// ---------------------------------------------------------------------------
// Fallback B (tiny ws): direct per-edge fp32.
// ---------------------------------------------------------------------------
__global__ void __launch_bounds__(256) edge_direct_kernel(
    const float* __restrict__ x, const void* __restrict__ ei,
    const float* __restrict__ ed, const float* __restrict__ w1,
    const float* __restrict__ b1, const float* __restrict__ w2,
    const float* __restrict__ b2, const unsigned int* __restrict__ flag,
    float* __restrict__ out, int num_edges, int num_nodes) {
    const int lane   = threadIdx.x & 63;
    const int wave   = (blockIdx.x * blockDim.x + threadIdx.x) >> 6;
    const int nwaves = (gridDim.x * blockDim.x) >> 6;
    const int c0     = lane << 2;

    const float4 w2v = *(const float4*)(w2 + c0);
    const float4 b1v = *(const float4*)(b1 + c0);
    float wt[4][4];
#pragma unroll
    for (int k = 0; k < 4; ++k)
        *(float4*)wt[k] = *(const float4*)(w1 + (size_t)(2 * GNN_IN + k) * HID + c0);
    const float b2v  = b2[0];
    const int   is64 = flag ? (int)(*flag) : 0;
    const float* w2p = (const float*)&w2v;
    const float* b1p = (const float*)&b1v;

    const int chunk = (num_edges + nwaves - 1) / nwaves;
    const int e0 = wave * chunk;
    const int e1 = min(num_edges, e0 + chunk);

    for (int e = e0; e < e1; ++e) {
        int row, col;
        if (is64) {
            const int4 v = ((const int4*)ei)[e];
            row = v.x; col = v.z;
        } else {
            const int2 v = ((const int2*)ei)[e];
            row = v.x; col = v.y;
        }
        row = min(max(row, 0), num_nodes - 1);
        col = min(max(col, 0), num_nodes - 1);
        const float4 edv = *(const float4*)(ed + (size_t)e * 4);
        const float* edp = (const float*)&edv;
        float h4[4];
#pragma unroll
        for (int jj = 0; jj < 4; ++jj) {
            float h = b1p[jj];
#pragma unroll
            for (int k = 0; k < 4; ++k) h = fmaf(edp[k], wt[k][jj], h);
            h4[jj] = h;
        }
        const float* xr = x + (size_t)row * GNN_IN;
        const float* xc = x + (size_t)col * GNN_IN;
        for (int k = 0; k < GNN_IN; ++k) {
            const float xv = xr[k];
            const float4 wv = *(const float4*)(w1 + (size_t)k * HID + c0);
            h4[0] = fmaf(xv, wv.x, h4[0]); h4[1] = fmaf(xv, wv.y, h4[1]);
            h4[2] = fmaf(xv, wv.z, h4[2]); h4[3] = fmaf(xv, wv.w, h4[3]);
        }
        for (int k = 0; k < GNN_IN; ++k) {
            const float xv = xc[k];
            const float4 wv = *(const float4*)(w1 + (size_t)(GNN_IN + k) * HID + c0);
            h4[0] = fmaf(xv, wv.x, h4[0]); h4[1] = fmaf(xv, wv.y, h4[1]);
            h4[2] = fmaf(xv, wv.z, h4[2]); h4[3] = fmaf(xv, wv.w, h4[3]);
        }
        float p = 0.f;
#pragma unroll
        for (int jj = 0; jj < 4; ++jj) p = fmaf(fmaxf(h4[jj], 0.f), w2p[jj], p);
#pragma unroll
        for (int off = 32; off >= 1; off >>= 1) p += __shfl_xor(p, off, 64);
        if (lane == 0) out[e] = 1.f / (1.f + __expf(-(p + b2v)));
    }
}

extern "C" void kernel_launch(void* const* d_in, const int* in_sizes, int n_in,
                              void* d_out, int out_size, void* d_ws, size_t ws_size,
                              hipStream_t stream) {
    const float* x  = (const float*)d_in[0];
    const void*  ei = d_in[1];
    const float* ed = (const float*)d_in[2];
    const float* w1 = (const float*)d_in[3];
    const float* b1 = (const float*)d_in[4];
    const float* w2 = (const float*)d_in[5];
    const float* b2 = (const float*)d_in[6];
    float* out = (float*)d_out;

    const int num_nodes = in_sizes[0] / GNN_IN;  // 10000
    const int num_edges = in_sizes[1] / 2;       // 640000

    unsigned int* flag = nullptr;
    if (ws_size >= 16) {
        flag = (unsigned int*)d_ws;
        detect_kernel<<<1, 64, 0, stream>>>((const unsigned int*)ei, flag);
    }

    const size_t ab_bytes   = (size_t)2 * num_nodes * HID * sizeof(__half);
    const size_t idx_bytes  = (size_t)num_edges * sizeof(int2);
    const size_t part_bytes = (size_t)NSPLIT * num_edges * sizeof(float);
    const size_t need_split = 256 + ab_bytes + idx_bytes + part_bytes;
    const size_t need_old   = 256 + ab_bytes;

    if (flag && ws_size >= need_split) {
        __half* AB      = (__half*)((char*)d_ws + 256);
        int2*   idx     = (int2*)((char*)d_ws + 256 + ab_bytes);
        float*  partial = (float*)((char*)d_ws + 256 + ab_bytes + idx_bytes);

        decode_kernel<<<(num_edges + 255) / 256, 256, 0, stream>>>(ei, flag, idx,
                                                                   num_edges);
        node_gemm_c4<<<(num_nodes + 15) / 16, 256, 0, stream>>>(x, w1, AB,
                                                                num_nodes);
        edge_split_kernel<<<2048, 256, 0, stream>>>(AB, idx, ed, w1, b1, w2,
                                                    partial, num_edges, num_nodes);
        combine_kernel<<<(num_edges / 4 + 255) / 256, 256, 0, stream>>>(
            partial, b2, out, num_edges);
    } else if (flag && ws_size >= need_old) {
        __half* AB = (__half*)((char*)d_ws + 256);
        node_gemm_c4<<<(num_nodes + 15) / 16, 256, 0, stream>>>(x, w1, AB,
                                                                num_nodes);
        __half* Bp = AB + (size_t)num_nodes * HID;
        edge_kernel_fp16<<<2048, 256, 0, stream>>>(AB, Bp, ei, ed, w1, b1, w2, b2,
                                                   flag, out, num_edges);
    } else {
        edge_direct_kernel<<<4096, 256, 0, stream>>>(x, ei, ed, w1, b1, w2, b2,
                                                     flag, out, num_edges, num_nodes);
    }
}